// Round 1
// baseline (237.044 us; speedup 1.0000x reference)
//
#include <hip/hip_runtime.h>

// Problem constants from setup_inputs(): shape (64, 16, 64, 64), fp32.
#define N_ 64
#define C_ 16
#define H_ 64
#define W_ 64
#define TRI_ ((N_ * (N_ + 1)) / 2)   // 2080 upper-triangle pairs (incl diag)

// ws layout (floats): [0..Np) mu_a_pooled | [Np..2Np) var_a | [2Np..3Np) mu_b_pooled | [3Np..4Np) var_b
// where Np = N*C*(H/k)*(W/k), computed on-device from kern.

__global__ void zero_out_kernel(float* out) {
    if (threadIdx.x == 0 && blockIdx.x == 0) out[0] = 0.0f;
}

__global__ void pool_kernel(const float* __restrict__ mu_a,
                            const float* __restrict__ lv_a,
                            const float* __restrict__ mu_b,
                            const float* __restrict__ lv_b,
                            const int* __restrict__ kern_p,
                            float* __restrict__ ws) {
    const int k = kern_p[0];
    const int Hp = H_ / k, Wp = W_ / k;
    const int Np = N_ * C_ * Hp * Wp;
    const float inv_k2 = 1.0f / (float)(k * k);
    const float inv_k4 = inv_k2 * inv_k2;
    const int total = 4 * Np;
    const float LOG2E = 1.44269504088896f;

    for (int p = blockIdx.x * blockDim.x + threadIdx.x; p < total;
         p += gridDim.x * blockDim.x) {
        const int a  = p / Np;          // which array
        const int r  = p - a * Np;      // pooled flat index within array
        const int pw = r % Wp;
        const int t1 = r / Wp;
        const int ph = t1 % Hp;
        const int nc = t1 / Hp;         // fused (n*C + c), contiguous

        const float* src = (a == 0) ? mu_a : (a == 1) ? lv_a : (a == 2) ? mu_b : lv_b;
        const bool is_var = (a & 1);

        const int base = nc * (H_ * W_) + (ph * k) * W_ + (pw * k);
        float s = 0.0f;
        for (int dy = 0; dy < k; ++dy) {
            const float* row = src + base + dy * W_;
            for (int dx = 0; dx < k; ++dx) {
                float x = row[dx];
                s += is_var ? __builtin_amdgcn_exp2f(x * LOG2E) : x;
            }
        }
        ws[(size_t)a * Np + r] = s * (is_var ? inv_k4 : inv_k2);
    }
}

// One block per (set, i, j) pair. Sets: 0 = vaa upper-tri, 1 = vbb upper-tri,
// 2 = vab full. Block-reduces sum over D, atomicAdd(weight * sum) to out.
__global__ __launch_bounds__(256) void pair_kernel(const float* __restrict__ ws,
                                                   const int* __restrict__ kern_p,
                                                   float* __restrict__ out) {
    const int k = kern_p[0];
    const int D  = C_ * (H_ / k) * (W_ / k);
    const int Np = N_ * D;

    const float* mu_a = ws;
    const float* va   = ws + (size_t)Np;
    const float* mu_b = ws + (size_t)2 * Np;
    const float* vb   = ws + (size_t)3 * Np;

    const int b = blockIdx.x;
    int i, j;
    float wgt;
    const float *mu1, *v1, *mu2, *v2;

    if (b < 2 * TRI_) {
        const int t = (b < TRI_) ? b : (b - TRI_);
        // triangular decode: t -> (i, j) with j <= i
        int ii = (int)((sqrtf(8.0f * (float)t + 1.0f) - 1.0f) * 0.5f);
        while ((ii + 1) * (ii + 2) / 2 <= t) ++ii;
        while (ii * (ii + 1) / 2 > t) --ii;
        i = ii;
        j = t - ii * (ii + 1) / 2;
        wgt = (i == j) ? 1.0f : 2.0f;
        if (b < TRI_) { mu1 = mu2 = mu_a; v1 = v2 = va; }
        else          { mu1 = mu2 = mu_b; v1 = v2 = vb; }
    } else {
        const int t = b - 2 * TRI_;
        i = t >> 6;          // N_ == 64
        j = t & (N_ - 1);
        wgt = -2.0f;
        mu1 = mu_a; v1 = va; mu2 = mu_b; v2 = vb;
    }

    const float4* M1 = (const float4*)(mu1 + (size_t)i * D);
    const float4* V1 = (const float4*)(v1  + (size_t)i * D);
    const float4* M2 = (const float4*)(mu2 + (size_t)j * D);
    const float4* V2 = (const float4*)(v2  + (size_t)j * D);

    const float NHALF_LOG2E = -0.721347520444482f;  // -0.5 * log2(e)
    float acc = 0.0f;
    const int D4 = D >> 2;
    for (int q = threadIdx.x; q < D4; q += blockDim.x) {
        float4 m1 = M1[q], s1 = V1[q], m2 = M2[q], s2 = V2[q];
#define TERM(mx1, sx1, mx2, sx2)                                   \
        {                                                          \
            float v  = (sx1) + (sx2);                              \
            float rs = __builtin_amdgcn_rsqf(v);                   \
            float rv = rs * rs;                                    \
            float d  = (mx1) - (mx2);                              \
            float e  = __builtin_amdgcn_exp2f(NHALF_LOG2E * d * d * rv); \
            acc += e * rs;                                         \
        }
        TERM(m1.x, s1.x, m2.x, s2.x)
        TERM(m1.y, s1.y, m2.y, s2.y)
        TERM(m1.z, s1.z, m2.z, s2.z)
        TERM(m1.w, s1.w, m2.w, s2.w)
#undef TERM
    }

    // wave reduce (width 64), then LDS across the 4 waves
    for (int off = 32; off > 0; off >>= 1)
        acc += __shfl_down(acc, off, 64);
    __shared__ float wsum[4];
    const int lane = threadIdx.x & 63;
    const int wid  = threadIdx.x >> 6;
    if (lane == 0) wsum[wid] = acc;
    __syncthreads();
    if (threadIdx.x == 0) {
        float s = wsum[0] + wsum[1] + wsum[2] + wsum[3];
        atomicAdd(out, wgt * s);
    }
}

extern "C" void kernel_launch(void* const* d_in, const int* in_sizes, int n_in,
                              void* d_out, int out_size, void* d_ws, size_t ws_size,
                              hipStream_t stream) {
    const float* mu_a = (const float*)d_in[0];
    const float* lv_a = (const float*)d_in[1];
    const float* mu_b = (const float*)d_in[2];
    const float* lv_b = (const float*)d_in[3];
    const int*   kern = (const int*)d_in[4];
    float* out = (float*)d_out;
    float* ws  = (float*)d_ws;

    zero_out_kernel<<<1, 64, 0, stream>>>(out);
    pool_kernel<<<2048, 256, 0, stream>>>(mu_a, lv_a, mu_b, lv_b, kern, ws);
    const int nblocks = 2 * TRI_ + N_ * N_;  // 8256
    pair_kernel<<<nblocks, 256, 0, stream>>>(ws, kern, out);
}

// Round 2
// 166.086 us; speedup vs baseline: 1.4272x; 1.4272x over previous
//
#include <hip/hip_runtime.h>

// Problem constants from setup_inputs(): shape (64, 16, 64, 64), fp32, kern=2.
#define N_ 64
#define C_ 16
#define H_ 64
#define W_ 64

// pair_kernel block decomposition: JT = 8 j's per block.
// tri sets (vaa, vbb): per i, tiles jt = 0..i/8  -> sum = 8*(1+..+8) = 288 blocks/set
// vab (full):          64 i * 8 jt               -> 512 blocks
#define TRI_BLOCKS 288
#define PAIR_BLOCKS (2 * TRI_BLOCKS + 512)   // 1088

// ws layout (floats): [0..Np) mu_a | [Np..2Np) var_a | [2Np..3Np) mu_b | [3Np..4Np) var_b

__global__ __launch_bounds__(256) void pool_kernel(
    const float* __restrict__ mu_a, const float* __restrict__ lv_a,
    const float* __restrict__ mu_b, const float* __restrict__ lv_b,
    const int* __restrict__ kern_p, float* __restrict__ ws,
    float* __restrict__ out) {
    if (blockIdx.x == 0 && threadIdx.x == 0) out[0] = 0.0f;  // pair runs after (stream order)

    const int k = kern_p[0];
    const float LOG2E = 1.44269504088896f;

    if (k == 2) {
        // Fast path: 4 contiguous pooled outputs per thread, all-shift indexing.
        const int Np = (N_ * C_ * H_ * W_) >> 2;  // 1048576
        const int Q  = Np >> 2;                   // 262144 quads per array
        const int total = 4 * Q;
        for (int g = blockIdx.x * blockDim.x + threadIdx.x; g < total;
             g += gridDim.x * blockDim.x) {
            const int a  = g >> 18;               // log2(Q) = 18
            const int r4 = g & (Q - 1);
            const int pw4 = (r4 & 7) << 2;        // Wp=32 -> 8 quads/row
            const int t   = r4 >> 3;
            const int ph  = t & 31;               // Hp=32
            const int nc  = t >> 5;
            const float* src = (a == 0) ? mu_a : (a == 1) ? lv_a : (a == 2) ? mu_b : lv_b;
            const bool is_var = (a & 1);
            const float* p0 = src + nc * (H_ * W_) + (ph * 2) * W_ + pw4 * 2;
            float4 r0a = *(const float4*)(p0);
            float4 r0b = *(const float4*)(p0 + 4);
            float4 r1a = *(const float4*)(p0 + W_);
            float4 r1b = *(const float4*)(p0 + W_ + 4);
            float o0, o1, o2, o3;
            if (is_var) {
#define E_(x) __builtin_amdgcn_exp2f((x) * LOG2E)
                o0 = E_(r0a.x) + E_(r0a.y) + E_(r1a.x) + E_(r1a.y);
                o1 = E_(r0a.z) + E_(r0a.w) + E_(r1a.z) + E_(r1a.w);
                o2 = E_(r0b.x) + E_(r0b.y) + E_(r1b.x) + E_(r1b.y);
                o3 = E_(r0b.z) + E_(r0b.w) + E_(r1b.z) + E_(r1b.w);
#undef E_
                const float s = 1.0f / 16.0f;     // 1/k^4
                o0 *= s; o1 *= s; o2 *= s; o3 *= s;
            } else {
                o0 = r0a.x + r0a.y + r1a.x + r1a.y;
                o1 = r0a.z + r0a.w + r1a.z + r1a.w;
                o2 = r0b.x + r0b.y + r1b.x + r1b.y;
                o3 = r0b.z + r0b.w + r1b.z + r1b.w;
                const float s = 0.25f;            // 1/k^2
                o0 *= s; o1 *= s; o2 *= s; o3 *= s;
            }
            *(float4*)(ws + (size_t)a * Np + (size_t)r4 * 4) = make_float4(o0, o1, o2, o3);
        }
    } else {
        // Generic fallback (any k dividing 64).
        const int Hp = H_ / k, Wp = W_ / k;
        const int Np = N_ * C_ * Hp * Wp;
        const float inv_k2 = 1.0f / (float)(k * k);
        const float inv_k4 = inv_k2 * inv_k2;
        const int total = 4 * Np;
        for (int p = blockIdx.x * blockDim.x + threadIdx.x; p < total;
             p += gridDim.x * blockDim.x) {
            const int a  = p / Np;
            const int r  = p - a * Np;
            const int pw = r % Wp;
            const int t1 = r / Wp;
            const int ph = t1 % Hp;
            const int nc = t1 / Hp;
            const float* src = (a == 0) ? mu_a : (a == 1) ? lv_a : (a == 2) ? mu_b : lv_b;
            const bool is_var = (a & 1);
            const int base = nc * (H_ * W_) + (ph * k) * W_ + (pw * k);
            float s = 0.0f;
            for (int dy = 0; dy < k; ++dy) {
                const float* row = src + base + dy * W_;
                for (int dx = 0; dx < k; ++dx) {
                    float x = row[dx];
                    s += is_var ? __builtin_amdgcn_exp2f(x * LOG2E) : x;
                }
            }
            ws[(size_t)a * Np + r] = s * (is_var ? inv_k4 : inv_k2);
        }
    }
}

// block = (set, i, jt): i-row chunk held in registers, 8 j-rows streamed against it.
__global__ __launch_bounds__(256) void pair_kernel(const float* __restrict__ ws,
                                                   const int* __restrict__ kern_p,
                                                   float* __restrict__ out) {
    const int k = kern_p[0];
    const int D  = C_ * (H_ / k) * (W_ / k);
    const int Np = N_ * D;

    const float* mu_a = ws;
    const float* va   = ws + (size_t)Np;
    const float* mu_b = ws + (size_t)2 * Np;
    const float* vb   = ws + (size_t)3 * Np;

    // ---- decode block -> (set, i, jt) ----
    const int b = blockIdx.x;
    int set, i, jt;
    if (b >= 2 * TRI_BLOCKS) {
        set = 2;
        const int t = b - 2 * TRI_BLOCKS;
        i  = t >> 3;
        jt = t & 7;
    } else {
        set = (b >= TRI_BLOCKS) ? 1 : 0;
        const int t = (b >= TRI_BLOCKS) ? (b - TRI_BLOCKS) : b;
        int g = 0;                               // i-group = i>>3; S(g)=4g(g+1) blocks before
        while (g < 7 && 4 * (g + 1) * (g + 2) <= t) ++g;
        const int r = t - 4 * g * (g + 1);
        i  = 8 * g + r / (g + 1);
        jt = r % (g + 1);
    }

    const float *mu1, *v1, *mu2, *v2;
    if (set == 0)      { mu1 = mu2 = mu_a; v1 = v2 = va; }
    else if (set == 1) { mu1 = mu2 = mu_b; v1 = v2 = vb; }
    else               { mu1 = mu_a; v1 = va; mu2 = mu_b; v2 = vb; }

    const int j0 = jt * 8;
    float wgt[8];
    for (int j8 = 0; j8 < 8; ++j8) {
        if (set == 2) wgt[j8] = -2.0f;
        else {
            const int j = j0 + j8;
            wgt[j8] = (j > i) ? 0.0f : (j == i) ? 1.0f : 2.0f;
        }
    }

    const float NHALF_LOG2E = -0.721347520444482f;  // -0.5 * log2(e)
#define TERM(mx1, sx1, mx2, sx2)                                         \
    {                                                                    \
        float v  = (sx1) + (sx2);                                        \
        float rs = __builtin_amdgcn_rsqf(v);                             \
        float d  = (mx1) - (mx2);                                        \
        float e  = __builtin_amdgcn_exp2f(NHALF_LOG2E * (d * d) * (rs * rs)); \
        a += e * rs;                                                     \
    }

    const float* Mi = mu1 + (size_t)i * D;
    const float* Vi = v1  + (size_t)i * D;
    float accs[8] = {0, 0, 0, 0, 0, 0, 0, 0};

    if (D == 16384) {
        // Fast path: 4 D-chunks of 4096; thread holds 16 i-elems (4x float4, stride 1024).
        const int t4 = threadIdx.x << 2;
        for (int c = 0; c < 4; ++c) {
            const int base = (c << 12) + t4;
            const float4 im0 = *(const float4*)(Mi + base);
            const float4 im1 = *(const float4*)(Mi + base + 1024);
            const float4 im2 = *(const float4*)(Mi + base + 2048);
            const float4 im3 = *(const float4*)(Mi + base + 3072);
            const float4 iv0 = *(const float4*)(Vi + base);
            const float4 iv1 = *(const float4*)(Vi + base + 1024);
            const float4 iv2 = *(const float4*)(Vi + base + 2048);
            const float4 iv3 = *(const float4*)(Vi + base + 3072);
            for (int j8 = 0; j8 < 8; ++j8) {
                const float* Mj = mu2 + (size_t)(j0 + j8) * D + base;
                const float* Vj = v2  + (size_t)(j0 + j8) * D + base;
                const float4 jm0 = *(const float4*)(Mj);
                const float4 jm1 = *(const float4*)(Mj + 1024);
                const float4 jm2 = *(const float4*)(Mj + 2048);
                const float4 jm3 = *(const float4*)(Mj + 3072);
                const float4 jv0 = *(const float4*)(Vj);
                const float4 jv1 = *(const float4*)(Vj + 1024);
                const float4 jv2 = *(const float4*)(Vj + 2048);
                const float4 jv3 = *(const float4*)(Vj + 3072);
                float a = 0.0f;
                TERM(im0.x, iv0.x, jm0.x, jv0.x) TERM(im0.y, iv0.y, jm0.y, jv0.y)
                TERM(im0.z, iv0.z, jm0.z, jv0.z) TERM(im0.w, iv0.w, jm0.w, jv0.w)
                TERM(im1.x, iv1.x, jm1.x, jv1.x) TERM(im1.y, iv1.y, jm1.y, jv1.y)
                TERM(im1.z, iv1.z, jm1.z, jv1.z) TERM(im1.w, iv1.w, jm1.w, jv1.w)
                TERM(im2.x, iv2.x, jm2.x, jv2.x) TERM(im2.y, iv2.y, jm2.y, jv2.y)
                TERM(im2.z, iv2.z, jm2.z, jv2.z) TERM(im2.w, iv2.w, jm2.w, jv2.w)
                TERM(im3.x, iv3.x, jm3.x, jv3.x) TERM(im3.y, iv3.y, jm3.y, jv3.y)
                TERM(im3.z, iv3.z, jm3.z, jv3.z) TERM(im3.w, iv3.w, jm3.w, jv3.w)
                accs[j8] += a;
            }
        }
    } else {
        // Generic fallback for any D.
        for (int j8 = 0; j8 < 8; ++j8) {
            const float* Mj = mu2 + (size_t)(j0 + j8) * D;
            const float* Vj = v2  + (size_t)(j0 + j8) * D;
            float a = 0.0f;
            for (int e = threadIdx.x; e < D; e += 256) {
                TERM(Mi[e], Vi[e], Mj[e], Vj[e])
            }
            accs[j8] = a;
        }
    }
#undef TERM

    float tot = 0.0f;
    for (int j8 = 0; j8 < 8; ++j8) tot += wgt[j8] * accs[j8];

    for (int off = 32; off > 0; off >>= 1)
        tot += __shfl_down(tot, off, 64);
    __shared__ float wsum[4];
    const int lane = threadIdx.x & 63;
    const int wid  = threadIdx.x >> 6;
    if (lane == 0) wsum[wid] = tot;
    __syncthreads();
    if (threadIdx.x == 0) {
        atomicAdd(out, wsum[0] + wsum[1] + wsum[2] + wsum[3]);
    }
}

extern "C" void kernel_launch(void* const* d_in, const int* in_sizes, int n_in,
                              void* d_out, int out_size, void* d_ws, size_t ws_size,
                              hipStream_t stream) {
    const float* mu_a = (const float*)d_in[0];
    const float* lv_a = (const float*)d_in[1];
    const float* mu_b = (const float*)d_in[2];
    const float* lv_b = (const float*)d_in[3];
    const int*   kern = (const int*)d_in[4];
    float* out = (float*)d_out;
    float* ws  = (float*)d_ws;

    pool_kernel<<<2048, 256, 0, stream>>>(mu_a, lv_a, mu_b, lv_b, kern, ws, out);
    pair_kernel<<<PAIR_BLOCKS, 256, 0, stream>>>(ws, kern, out);
}